// Round 3
// baseline (166.574 us; speedup 1.0000x reference)
//
#include <hip/hip_runtime.h>

#define NRBF 20
#define FOUT 16
#define NA 768
#define NB 4
#define NT 48            // m-tiles per row (768/16)

// Round-6: (a) operand-swapped MFMA -> dense float4 stores, (b) n<->m symmetry.
//
// (a) Swap: compute D = W * RBF^T instead of RBF * W^T. Fragment construction
//   is IDENTICAL to round-5 (A-side lane l&15 indexes W's f-row, B-side lane
//   l&15 indexes the tile's m, same gauge k = (l>>4)*8 + j, zero-pad lives on
//   the W side so the k>=20 rbf garbage still multiplies 0). Only the argument
//   order and the store addressing change. D layout: col = l&15 = m-sub,
//   row = (l>>4)*4 + reg = f -> each lane holds 4 CONSECUTIVE f for one m
//   -> one global_store_dwordx4 per tile, wave covers a dense 1KB span
//   (lane-permuted but contiguous), vs 4 stores x 16 scattered 64B segments.
//
// (b) Symmetry: out[b,n,m,:] == out[b,m,n,:] exactly (dx*dx is sign-invariant,
//   identical fmaf tree both directions -> bitwise equal). Block i owns row
//   pair (i, 767-i); upper-tri tile counts (48-q) + (q+1) = 49 = constant ->
//   perfect load balance at HALF the compute. Each tile stores dense
//   out[b,row,m,4g..] AND mirror out[b,m,row,4g..] (16B/lane; 4 lanes per m
//   form one 64B segment). Boundary-tile overlaps write bitwise-identical
//   values -> benign.
//
// Occupancy: 384x4 = 1536 blocks = 6 blocks/CU, all waves resident
//   (24 waves/CU); __launch_bounds__(256,6) keeps VGPR <= ~84, no spill.

typedef _Float16 f16x8 __attribute__((ext_vector_type(8)));
typedef float    f32x4 __attribute__((ext_vector_type(4)));

__global__ __launch_bounds__(256, 6) void cfconv_kernel(
    const float* __restrict__ coords,  // [NB, NA, 3] fp32
    const float* __restrict__ Ww,      // [FOUT, NRBF] fp32
    const float* __restrict__ Wb,      // [FOUT] fp32
    float* __restrict__ out)           // [NB, NA, NA, FOUT] fp32
{
    __shared__ float cm[NA * 3];       // batch's m-coordinates

    const int tid = threadIdx.x;
    const int i   = blockIdx.x;        // row-pair id 0..383
    const int b   = blockIdx.y;

    const int n1 = i;                  // handles m-tiles q..47
    const int n2 = NA - 1 - i;         // handles m-tiles (47-q)..47
    const int q  = n1 >> 4;
    const int ntile1 = NT - q;         // tiles for row n1; total = 49

    const float* cb = coords + (size_t)b * NA * 3;
    for (int idx = tid; idx < NA * 3; idx += 256) cm[idx] = cb[idx];
    __syncthreads();

    const int w  = tid >> 6;   // wave id 0..3
    const int l  = tid & 63;
    const int mi = l & 15;     // m sub-index (B col / D col)
    const int g  = l >> 4;     // k-group; this lane's D rows are f = 4g+0..3

    // A fragment = W[f = mi][k = 8g+j], zero-padded k >= 20
    f16x8 afrag;
    #pragma unroll
    for (int j = 0; j < 8; ++j) {
        const int k = g * 8 + j;
        afrag[j] = (k < NRBF) ? (_Float16)Ww[mi * NRBF + k] : (_Float16)0.0f;
    }
    // C-in rows are f = 4g+r -> bias per reg
    const f32x4 cinit = { Wb[4*g+0], Wb[4*g+1], Wb[4*g+2], Wb[4*g+3] };

    const float x1 = cb[n1*3+0], y1 = cb[n1*3+1], z1 = cb[n1*3+2];
    const float x2 = cb[n2*3+0], y2 = cb[n2*3+1], z2 = cb[n2*3+2];

    const float mu0  = 0.1f * (8 * g);          // segment-start mu
    const float tcst = 0.2f * (8 * g) + 0.1f;   // t_{k0+1} exponent offset
    const float u    = 0.81873075308f;          // e^{-0.2}

    float* ob = out + (size_t)b * NA * NA * FOUT;

    for (int idx = w; idx < NT + 1; idx += 4) {
        // wave-uniform row/tile select (idx is uniform across the wave)
        const bool first = (idx < ntile1);
        const int  row   = first ? n1 : n2;
        const int  t     = first ? (q + idx) : (NT - 1 - q + idx - ntile1);
        const float xn   = first ? x1 : x2;
        const float yn   = first ? y1 : y2;
        const float zn   = first ? z1 : z2;

        const int m  = t * 16 + mi;
        // cm word idx 3m: 16 lanes stride-3, gcd(3,32)=1 -> distinct banks;
        // 4 k-groups share addresses -> broadcast.
        const float dx = xn - cm[m*3+0];
        const float dy = yn - cm[m*3+1];
        const float dz = zn - cm[m*3+2];
        const float d2 = fmaf(dx, dx, fmaf(dy, dy, dz * dz));
        const float d  = sqrtf(d2);

        const float dd = d - mu0;
        float r  = __expf(-10.0f * dd * dd);    // r_{k0}
        float tt = __expf(2.0f * d - tcst);     // ratio t_{k0+1}

        f16x8 bfrag;                            // B[k = 8g+j][m = mi]
        bfrag[0] = (_Float16)r;
        #pragma unroll
        for (int j = 1; j < 8; ++j) {
            r *= tt;                            // r_{k0+j}
            tt *= u;
            bfrag[j] = (_Float16)r;
        }

        f32x4 acc = cinit;                      // D = W * RBF^T + bias
        acc = __builtin_amdgcn_mfma_f32_16x16x32_f16(afrag, bfrag, acc, 0, 0, 0);

        // dense: out[b, row, m, 4g+0..3]  (wave = permuted-contiguous 1KB)
        *reinterpret_cast<f32x4*>(ob + ((size_t)row * NA + m) * FOUT + 4*g) = acc;
        // mirror: out[b, m, row, 4g+0..3] (4 lanes per m -> 64B segments)
        *reinterpret_cast<f32x4*>(ob + ((size_t)m * NA + row) * FOUT + 4*g) = acc;
    }
}

extern "C" void kernel_launch(void* const* d_in, const int* in_sizes, int n_in,
                              void* d_out, int out_size, void* d_ws, size_t ws_size,
                              hipStream_t stream) {
    const float* coords = (const float*)d_in[0];
    const float* Ww     = (const float*)d_in[1];
    const float* Wb     = (const float*)d_in[2];
    float* out          = (float*)d_out;

    dim3 grid(NA / 2, NB);   // (row-pair, b)
    cfconv_kernel<<<grid, 256, 0, stream>>>(coords, Ww, Wb, out);
}